// Round 2
// baseline (312.555 us; speedup 1.0000x reference)
//
#include <hip/hip_runtime.h>

// MRGCO: real-FFT tensor-product RGCN layer.
// cos-transform (real(fft)) along k has rank 5 (j and 8-j rows equal); the
// ifft/fft round-trip between the two tensor products cancels exactly.
// Pipeline: k_pre (A->Af, X->Xft, W->Wft, all bf16) ; gemm_k split-K=4
// (C1p fp32 partials) ; k_red (sum 4 -> C1 bf16) ; gemm_k (C2 fp32) ; k_combine.

typedef __bf16 bf16_t;
typedef __bf16 bf16x2 __attribute__((ext_vector_type(2)));
typedef __bf16 bf16x8 __attribute__((ext_vector_type(8)));
typedef float f32x4 __attribute__((ext_vector_type(4)));

#define R2C 0.70710678118654752f

__device__ __forceinline__ void fwd5(const float x[8], float F[5]) {
  float s04 = x[0] + x[4], d04 = x[0] - x[4];
  float s26 = x[2] + x[6];
  float s15 = x[1] + x[5], s37 = x[3] + x[7];
  float t = (x[1] + x[7]) - (x[3] + x[5]);
  float e = s04 + s26, o = s15 + s37;
  F[0] = e + o;
  F[1] = d04 + R2C * t;
  F[2] = s04 - s26;
  F[3] = d04 - R2C * t;
  F[4] = e - o;
}

// Fused input transforms. blocks [0,8192): A ; [8192,9216): X ; [9216,9472): W.
__global__ __launch_bounds__(256) void k_pre(const float* __restrict__ X,
                                             const float* __restrict__ A,
                                             const float* __restrict__ W,
                                             bf16_t* __restrict__ Xft,
                                             bf16_t* __restrict__ Af,
                                             bf16_t* __restrict__ Wft) {
  int b = blockIdx.x;
  if (b < 8192) {
    // Af[j][idx] for two consecutive idx = n*2048+m (coalesced 64B reads, 4B writes)
    size_t t = (size_t)b * 256 + threadIdx.x;
    size_t idx = t * 2;
    const float4* p = (const float4*)(A + idx * 8);
    float4 q0 = p[0], q1 = p[1], q2 = p[2], q3 = p[3];
    float x0[8] = {q0.x, q0.y, q0.z, q0.w, q1.x, q1.y, q1.z, q1.w};
    float x1[8] = {q2.x, q2.y, q2.z, q2.w, q3.x, q3.y, q3.z, q3.w};
    float F0[5], F1[5];
    fwd5(x0, F0);
    fwd5(x1, F1);
#pragma unroll
    for (int j = 0; j < 5; j++) {
      bf16x2 v = {(bf16_t)F0[j], (bf16_t)F1[j]};
      *(bf16x2*)(Af + (size_t)j * 4194304 + idx) = v;
    }
  } else if (b < 9216) {
    // Xft[j][h][m], two consecutive m per thread
    size_t t = (size_t)(b - 8192) * 256 + threadIdx.x;  // 0..262143
    int h = (int)(t >> 10);
    int m = (int)(t & 1023) * 2;
    const float4* p0 = (const float4*)(X + ((size_t)m * 256 + h) * 8);
    const float4* p1 = (const float4*)(X + ((size_t)(m + 1) * 256 + h) * 8);
    float4 a0 = p0[0], b0 = p0[1], a1 = p1[0], b1 = p1[1];
    float x0[8] = {a0.x, a0.y, a0.z, a0.w, b0.x, b0.y, b0.z, b0.w};
    float x1[8] = {a1.x, a1.y, a1.z, a1.w, b1.x, b1.y, b1.z, b1.w};
    float F0[5], F1[5];
    fwd5(x0, F0);
    fwd5(x1, F1);
    size_t base = (size_t)h * 2048 + m;
#pragma unroll
    for (int j = 0; j < 5; j++) {
      bf16x2 v = {(bf16_t)F0[j], (bf16_t)F1[j]};
      *(bf16x2*)(Xft + (size_t)j * 524288 + base) = v;
    }
  } else {
    // Wft[j][h][h'] = s_j * sum_k W[h'][h][k] c_jk
    int h = b - 9216;
    int hp = threadIdx.x;
    const float4* p = (const float4*)(W + ((size_t)hp * 256 + h) * 8);
    float4 a = p[0], bb = p[1];
    float x[8] = {a.x, a.y, a.z, a.w, bb.x, bb.y, bb.z, bb.w};
    float F[5];
    fwd5(x, F);
    const float sc[5] = {0.125f, 0.25f, 0.25f, 0.25f, 0.125f};
    size_t base = (size_t)h * 256 + hp;
#pragma unroll
    for (int j = 0; j < 5; j++)
      Wft[(size_t)j * 65536 + base] = (bf16_t)(F[j] * sc[j]);
  }
}

// Batched bf16 GEMM with optional split-K. blockIdx.z = s*5 + j ; k-range
// [s*KS, (s+1)*KS). C plane = blockIdx.z (so partials land at [s][j]).
// 128x128 tile, BK=64, 4 waves 64x64, 16x16x32 MFMA, XOR-swizzled LDS,
// register prefetch of the next K-tile issued during the MFMA phase.
__global__ __launch_bounds__(256) void gemm_k(const bf16_t* __restrict__ A,
                                              const bf16_t* __restrict__ B,
                                              float* __restrict__ C, int K,
                                              int KS, size_t ap, size_t bp,
                                              size_t cp) {
  __shared__ bf16_t As[128 * 64];
  __shared__ bf16_t Bs[128 * 64];
  const int z = blockIdx.z, j = z % 5, s = z / 5;
  const bf16_t* Aj = A + (size_t)j * ap;
  const bf16_t* Bj = B + (size_t)j * bp;
  float* Cj = C + (size_t)z * cp;
  const int n0 = blockIdx.x * 128, h0 = blockIdx.y * 128;
  const int tid = threadIdx.x;
  const int wv = tid >> 6, ln = tid & 63;
  const int quad = ln >> 4, l16 = ln & 15;
  const int wn = (wv & 1) * 64, wh = (wv >> 1) * 64;
  const int k0 = s * KS, k1 = k0 + KS;

  const bf16_t* pa[4];
  const bf16_t* pb[4];
  int dsts[4];
#pragma unroll
  for (int t = 0; t < 4; t++) {
    int slot = tid + t * 256;
    int row = slot >> 3, c16 = slot & 7;
    dsts[t] = row * 64 + ((c16 ^ (row & 7)) << 3);
    pa[t] = Aj + (size_t)(n0 + row) * K + k0 + c16 * 8;
    pb[t] = Bj + (size_t)(h0 + row) * K + k0 + c16 * 8;
  }
  uint4 va[4], vb[4];
#pragma unroll
  for (int t = 0; t < 4; t++) {
    va[t] = *(const uint4*)pa[t];
    vb[t] = *(const uint4*)pb[t];
  }

  f32x4 acc[4][4] = {};
  for (int kk = k0; kk < k1; kk += 64) {
    __syncthreads();
#pragma unroll
    for (int t = 0; t < 4; t++) {
      *(uint4*)(As + dsts[t]) = va[t];
      *(uint4*)(Bs + dsts[t]) = vb[t];
    }
    __syncthreads();
    if (kk + 64 < k1) {
#pragma unroll
      for (int t = 0; t < 4; t++) {
        pa[t] += 64;
        pb[t] += 64;
        va[t] = *(const uint4*)pa[t];
        vb[t] = *(const uint4*)pb[t];
      }
    }
#pragma unroll
    for (int kh = 0; kh < 2; kh++) {
      bf16x8 af[4], bfr[4];
      int c16 = kh * 4 + quad;
#pragma unroll
      for (int i = 0; i < 4; i++) {
        int ra = wn + i * 16 + l16;
        int rb = wh + i * 16 + l16;
        af[i] = *(const bf16x8*)(As + ra * 64 + ((c16 ^ (ra & 7)) << 3));
        bfr[i] = *(const bf16x8*)(Bs + rb * 64 + ((c16 ^ (rb & 7)) << 3));
      }
#pragma unroll
      for (int i = 0; i < 4; i++)
#pragma unroll
        for (int t = 0; t < 4; t++)
          acc[i][t] = __builtin_amdgcn_mfma_f32_16x16x32_bf16(af[i], bfr[t],
                                                              acc[i][t], 0, 0, 0);
    }
  }
  // C/D layout: col = lane&15, row = quad*4 + reg
#pragma unroll
  for (int i = 0; i < 4; i++) {
#pragma unroll
    for (int t = 0; t < 4; t++) {
      int hc = h0 + wh + t * 16 + l16;
#pragma unroll
      for (int rg = 0; rg < 4; rg++) {
        int nr = n0 + wn + i * 16 + quad * 4 + rg;
        Cj[(size_t)nr * 256 + hc] = acc[i][t][rg];
      }
    }
  }
}

// C1[idx] = bf16( sum_s C1p[s][idx] ), idx over 5*2048*256, 2 per thread
__global__ __launch_bounds__(256) void k_red(const float* __restrict__ C1p,
                                             bf16_t* __restrict__ C1) {
  size_t idx = ((size_t)blockIdx.x * 256 + threadIdx.x) * 2;
  float2 a0 = *(const float2*)(C1p + idx);
  float2 a1 = *(const float2*)(C1p + 2621440 + idx);
  float2 a2 = *(const float2*)(C1p + 2 * 2621440 + idx);
  float2 a3 = *(const float2*)(C1p + 3 * 2621440 + idx);
  bf16x2 v = {(bf16_t)(a0.x + a1.x + a2.x + a3.x),
              (bf16_t)(a0.y + a1.y + a2.y + a3.y)};
  *(bf16x2*)(C1 + idx) = v;
}

// out[n][h][k] = sum_j c_jk * C2_j[n][h]
__global__ __launch_bounds__(256) void k_combine(const float* __restrict__ C2,
                                                 float* __restrict__ out) {
  size_t idx = (size_t)blockIdx.x * 256 + threadIdx.x;
  float c0 = C2[idx];
  float c1 = C2[524288 + idx];
  float c2 = C2[2 * 524288 + idx];
  float c3 = C2[3 * 524288 + idx];
  float c4 = C2[4 * 524288 + idx];
  float o0 = c0 + c1 + c2 + c3 + c4;
  float o4 = c0 - c1 + c2 - c3 + c4;
  float o2 = c0 - c2 + c4;
  float rt = R2C * (c1 - c3);
  float o1 = c0 + rt - c4;
  float o3 = c0 - rt - c4;
  float4* op = (float4*)(out + idx * 8);
  op[0] = make_float4(o0, o1, o2, o3);
  op[1] = make_float4(o4, o3, o2, o1);
}

extern "C" void kernel_launch(void* const* d_in, const int* in_sizes, int n_in,
                              void* d_out, int out_size, void* d_ws, size_t ws_size,
                              hipStream_t stream) {
  const float* X = (const float*)d_in[0];   // (2048,256,8)
  const float* A = (const float*)d_in[1];   // (2048,2048,8)
  const float* W = (const float*)d_in[2];   // (256,256,8)
  float* out = (float*)d_out;               // (2048,256,8)
  char* ws = (char*)d_ws;

  bf16_t* Af  = (bf16_t*)(ws);               // 5*2048*2048*2  = 41943040
  bf16_t* Xft = (bf16_t*)(ws + 41943040);    // 5*256*2048*2   =  5242880
  bf16_t* Wft = (bf16_t*)(ws + 47185920);    // 5*256*256*2    =   655360
  float*  C1p = (float*) (ws + 47841280);    // 4*5*2048*256*4 = 41943040
  bf16_t* C1  = (bf16_t*)(ws + 89784320);    // 5*2048*256*2   =  5242880
  float*  C2  = (float*) (ws + 95027200);    // 5*2048*256*4   = 10485760
                                             // total 105512960 B

  k_pre<<<dim3(9472), 256, 0, stream>>>(X, A, W, Xft, Af, Wft);
  // gemm1: split-K=4 -> z = s*5+j, 640 blocks
  gemm_k<<<dim3(16, 2, 20), 256, 0, stream>>>(Af, Xft, C1p, 2048, 512,
                                              (size_t)4194304, (size_t)524288,
                                              (size_t)524288);
  k_red<<<dim3(5120), 256, 0, stream>>>(C1p, C1);
  // gemm2: no split, z = j
  gemm_k<<<dim3(16, 2, 5), 256, 0, stream>>>(C1, Wft, C2, 256, 256,
                                             (size_t)524288, (size_t)65536,
                                             (size_t)524288);
  k_combine<<<dim3(2048), 256, 0, stream>>>(C2, out);
}

// Round 3
// 288.442 us; speedup vs baseline: 1.0836x; 1.0836x over previous
//
#include <hip/hip_runtime.h>

// MRGCO: real-FFT tensor-product RGCN layer.
// real(fft) along k (len 8) = rank-5 cosine transform (j and 8-j rows equal);
// the ifft->fft round-trip between the two tensor products cancels exactly.
// Pipeline: k_pre (A->Af, X->Xft, W->Wft, bf16, XOR-swizzled layout) ;
// gemm_lds C1=Af@Xft (bf16, swizzled out) ; gemm_lds C2=C1@Wft (fp32) ; k_combine.
//
// Swizzle: logical element (row r, col c) of a K-contiguous operand is stored at
//   r*K + (c&~63) + ((((c>>3)&7) ^ (r&7))<<3) + (c&7)
// so a LINEAR wave-uniform global_load_lds DMA (16B/lane) lands tiles in LDS
// already bank-swizzled; ds_read_b128 fragment reads stay conflict-free.

typedef __bf16 bf16_t;
typedef __bf16 bf16x2 __attribute__((ext_vector_type(2)));
typedef __bf16 bf16x8 __attribute__((ext_vector_type(8)));
typedef float f32x4 __attribute__((ext_vector_type(4)));

#define R2C 0.70710678118654752f

__device__ __forceinline__ size_t swz(int r, int c, int K) {
  return (size_t)r * K + (c & ~63) + ((((c >> 3) & 7) ^ (r & 7)) << 3) + (c & 7);
}

__device__ __forceinline__ void async_cp16(const void* g, void* l) {
  __builtin_amdgcn_global_load_lds((const __attribute__((address_space(1))) char*)g,
                                   (__attribute__((address_space(3))) char*)l,
                                   16, 0, 0);
}

__device__ __forceinline__ void fwd5(const float x[8], float F[5]) {
  float s04 = x[0] + x[4], d04 = x[0] - x[4];
  float s26 = x[2] + x[6];
  float s15 = x[1] + x[5], s37 = x[3] + x[7];
  float t = (x[1] + x[7]) - (x[3] + x[5]);
  float e = s04 + s26, o = s15 + s37;
  F[0] = e + o;
  F[1] = d04 + R2C * t;
  F[2] = s04 - s26;
  F[3] = d04 - R2C * t;
  F[4] = e - o;
}

// Fused input transforms. blocks [0,8192): A ; [8192,9216): X ; [9216,9472): W.
__global__ __launch_bounds__(256) void k_pre(const float* __restrict__ X,
                                             const float* __restrict__ A,
                                             const float* __restrict__ W,
                                             bf16_t* __restrict__ Xft,
                                             bf16_t* __restrict__ Af,
                                             bf16_t* __restrict__ Wft) {
  int b = blockIdx.x;
  if (b < 8192) {
    // Af[j][n][m] swizzled; two consecutive m per thread (same 8-chunk, m even)
    size_t t = (size_t)b * 256 + threadIdx.x;
    size_t idx = t * 2;                 // n*2048 + m
    int n = (int)(idx >> 11), m = (int)(idx & 2047);
    const float4* p = (const float4*)(A + idx * 8);
    float4 q0 = p[0], q1 = p[1], q2 = p[2], q3 = p[3];
    float x0[8] = {q0.x, q0.y, q0.z, q0.w, q1.x, q1.y, q1.z, q1.w};
    float x1[8] = {q2.x, q2.y, q2.z, q2.w, q3.x, q3.y, q3.z, q3.w};
    float F0[5], F1[5];
    fwd5(x0, F0);
    fwd5(x1, F1);
    size_t pos = swz(n, m, 2048);
#pragma unroll
    for (int j = 0; j < 5; j++) {
      bf16x2 v = {(bf16_t)F0[j], (bf16_t)F1[j]};
      *(bf16x2*)(Af + (size_t)j * 4194304 + pos) = v;
    }
  } else if (b < 9216) {
    // X: coalesced reads (2 consecutive (m,h) pairs in X memory order),
    // scattered 2B swizzled writes into Xft[j][h][m] (5MB total, L2-absorbed)
    size_t t = (size_t)(b - 8192) * 256 + threadIdx.x;
    size_t p0 = t * 2;                  // m*256 + h
#pragma unroll
    for (int u = 0; u < 2; u++) {
      size_t pp = p0 + u;
      int m = (int)(pp >> 8), h = (int)(pp & 255);
      const float4* p = (const float4*)(X + pp * 8);
      float4 a = p[0], bb = p[1];
      float x[8] = {a.x, a.y, a.z, a.w, bb.x, bb.y, bb.z, bb.w};
      float F[5];
      fwd5(x, F);
      size_t pos = swz(h, m, 2048);
#pragma unroll
      for (int j = 0; j < 5; j++)
        Xft[(size_t)j * 524288 + pos] = (bf16_t)F[j];
    }
  } else {
    // Wft[j][h][h'] = s_j * sum_k W[h'][h][k] c_jk, swizzled
    int h = b - 9216;
    int hp = threadIdx.x;
    const float4* p = (const float4*)(W + ((size_t)hp * 256 + h) * 8);
    float4 a = p[0], bb = p[1];
    float x[8] = {a.x, a.y, a.z, a.w, bb.x, bb.y, bb.z, bb.w};
    float F[5];
    fwd5(x, F);
    const float sc[5] = {0.125f, 0.25f, 0.25f, 0.25f, 0.125f};
    size_t pos = swz(h, hp, 256);
#pragma unroll
    for (int j = 0; j < 5; j++)
      Wft[(size_t)j * 65536 + pos] = (bf16_t)(F[j] * sc[j]);
  }
}

// Batched bf16 GEMM, 128x128 tile, BK=64, 4 waves (64x64 each), 16x16x32 MFMA.
// Operands in swizzled layout; staging via global_load_lds width-16 (linear
// lane->LDS mapping preserves the swizzle). SWZ_OUT: store C swizzled (bf16
// feeding the next GEMM) or linear (fp32 final).
template <typename OutT, bool SWZ_OUT>
__global__ __launch_bounds__(256) void gemm_lds(const bf16_t* __restrict__ A,
                                                const bf16_t* __restrict__ B,
                                                OutT* __restrict__ C, int K,
                                                size_t ap, size_t bp, size_t cp) {
  __shared__ bf16_t As[128 * 64];
  __shared__ bf16_t Bs[128 * 64];
  const int j = blockIdx.z;
  const bf16_t* Aj = A + (size_t)j * ap;
  const bf16_t* Bj = B + (size_t)j * bp;
  OutT* Cj = C + (size_t)j * cp;
  const int n0 = blockIdx.x * 128, h0 = blockIdx.y * 128;
  const int tid = threadIdx.x;
  const int wv = tid >> 6, ln = tid & 63;
  const int quad = ln >> 4, l16 = ln & 15;
  const int wn = (wv & 1) * 64, wh = (wv >> 1) * 64;

  // staging: 4 rounds x 256 lanes; slot -> (row, chunk); LDS dest is linear
  const bf16_t* ga[4];
  const bf16_t* gb[4];
  bf16_t* la[4];
  bf16_t* lb[4];
#pragma unroll
  for (int s = 0; s < 4; s++) {
    int slot = s * 256 + tid;
    int row = slot >> 3, c16 = slot & 7;
    ga[s] = Aj + (size_t)(n0 + row) * K + c16 * 8;
    gb[s] = Bj + (size_t)(h0 + row) * K + c16 * 8;
    int base = (s * 256 + wv * 64) * 8;  // wave-uniform element offset
    la[s] = As + base;
    lb[s] = Bs + base;
  }

  f32x4 acc[4][4] = {};
  for (int kk = 0; kk < K; kk += 64) {
    __syncthreads();
#pragma unroll
    for (int s = 0; s < 4; s++) {
      async_cp16(ga[s] + kk, la[s]);
      async_cp16(gb[s] + kk, lb[s]);
    }
    __syncthreads();
#pragma unroll
    for (int kh = 0; kh < 2; kh++) {
      bf16x8 af[4], bfr[4];
      int c16 = kh * 4 + quad;
#pragma unroll
      for (int i = 0; i < 4; i++) {
        int ra = wn + i * 16 + l16;
        int rb = wh + i * 16 + l16;
        af[i] = *(const bf16x8*)(As + ra * 64 + ((c16 ^ (ra & 7)) << 3));
        bfr[i] = *(const bf16x8*)(Bs + rb * 64 + ((c16 ^ (rb & 7)) << 3));
      }
#pragma unroll
      for (int i = 0; i < 4; i++)
#pragma unroll
        for (int t = 0; t < 4; t++)
          acc[i][t] = __builtin_amdgcn_mfma_f32_16x16x32_bf16(af[i], bfr[t],
                                                              acc[i][t], 0, 0, 0);
    }
  }
  // C/D layout: col = lane&15, row = quad*4 + reg
#pragma unroll
  for (int i = 0; i < 4; i++) {
#pragma unroll
    for (int t = 0; t < 4; t++) {
      int hc = h0 + wh + t * 16 + l16;
#pragma unroll
      for (int rg = 0; rg < 4; rg++) {
        int nr = n0 + wn + i * 16 + quad * 4 + rg;
        size_t off = SWZ_OUT ? swz(nr, hc, 256) : (size_t)nr * 256 + hc;
        Cj[off] = (OutT)acc[i][t][rg];
      }
    }
  }
}

// out[n][h][k] = sum_j c_jk * C2_j[n][h]  (ifft scales folded into Wft)
__global__ __launch_bounds__(256) void k_combine(const float* __restrict__ C2,
                                                 float* __restrict__ out) {
  size_t idx = (size_t)blockIdx.x * 256 + threadIdx.x;
  float c0 = C2[idx];
  float c1 = C2[524288 + idx];
  float c2 = C2[2 * 524288 + idx];
  float c3 = C2[3 * 524288 + idx];
  float c4 = C2[4 * 524288 + idx];
  float o0 = c0 + c1 + c2 + c3 + c4;
  float o4 = c0 - c1 + c2 - c3 + c4;
  float o2 = c0 - c2 + c4;
  float rt = R2C * (c1 - c3);
  float o1 = c0 + rt - c4;
  float o3 = c0 - rt - c4;
  float4* op = (float4*)(out + idx * 8);
  op[0] = make_float4(o0, o1, o2, o3);
  op[1] = make_float4(o4, o3, o2, o1);
}

extern "C" void kernel_launch(void* const* d_in, const int* in_sizes, int n_in,
                              void* d_out, int out_size, void* d_ws, size_t ws_size,
                              hipStream_t stream) {
  const float* X = (const float*)d_in[0];   // (2048,256,8)
  const float* A = (const float*)d_in[1];   // (2048,2048,8)
  const float* W = (const float*)d_in[2];   // (256,256,8)
  float* out = (float*)d_out;               // (2048,256,8)
  char* ws = (char*)d_ws;

  bf16_t* Af  = (bf16_t*)(ws);              // 5*2048*2048*2 = 41943040
  bf16_t* Xft = (bf16_t*)(ws + 41943040);   // 5*256*2048*2  =  5242880
  bf16_t* Wft = (bf16_t*)(ws + 47185920);   // 5*256*256*2   =   655360
  bf16_t* C1  = (bf16_t*)(ws + 47841280);   // 5*2048*256*2  =  5242880
  float*  C2  = (float*) (ws + 53084160);   // 5*2048*256*4  = 10485760
                                            // total 63569920 B

  k_pre<<<dim3(9472), 256, 0, stream>>>(X, A, W, Xft, Af, Wft);
  gemm_lds<bf16_t, true><<<dim3(16, 2, 5), 256, 0, stream>>>(
      Af, Xft, C1, 2048, (size_t)4194304, (size_t)524288, (size_t)524288);
  gemm_lds<float, false><<<dim3(16, 2, 5), 256, 0, stream>>>(
      C1, Wft, C2, 256, (size_t)524288, (size_t)65536, (size_t)524288);
  k_combine<<<dim3(2048), 256, 0, stream>>>(C2, out);
}

// Round 4
// 256.053 us; speedup vs baseline: 1.2207x; 1.1265x over previous
//
#include <hip/hip_runtime.h>

// MRGCO: real-FFT tensor-product RGCN layer.
// real(fft) along k (len 8) = rank-5 cosine transform (j and 8-j rows equal);
// the ifft->fft round-trip between the two tensor products cancels exactly.
// Pipeline: k_pre (A->Af, X->Xft via LDS transpose, W->Wft, bf16, XOR-swizzled
// layout) ; gemm_lds C1=Af@Xft (bf16, swizzled out) ; gemm_lds C2=C1@Wft (fp32) ;
// k_combine.
//
// Swizzle: logical (row r, col c) of a K-contiguous operand stored at
//   r*K + (c&~63) + ((((c>>3)&7) ^ (r&7))<<3) + (c&7)
// so a LINEAR wave-uniform global_load_lds DMA lands tiles in LDS already
// bank-swizzled; ds_read_b128 fragment reads stay conflict-free.
// GEMM K-loop: double-buffered LDS, raw s_barrier + manual s_waitcnt vmcnt(8)
// so the next tile's DMA stays in flight across the barrier (m139/AITER style).

typedef __bf16 bf16_t;
typedef __bf16 bf16x2 __attribute__((ext_vector_type(2)));
typedef __bf16 bf16x8 __attribute__((ext_vector_type(8)));
typedef float f32x4 __attribute__((ext_vector_type(4)));

#define R2C 0.70710678118654752f

__device__ __forceinline__ size_t swz(int r, int c, int K) {
  return (size_t)r * K + (c & ~63) + ((((c >> 3) & 7) ^ (r & 7)) << 3) + (c & 7);
}

__device__ __forceinline__ void async_cp16(const void* g, void* l) {
  __builtin_amdgcn_global_load_lds((const __attribute__((address_space(1))) char*)g,
                                   (__attribute__((address_space(3))) char*)l,
                                   16, 0, 0);
}

__device__ __forceinline__ void fwd5(const float x[8], float F[5]) {
  float s04 = x[0] + x[4], d04 = x[0] - x[4];
  float s26 = x[2] + x[6];
  float s15 = x[1] + x[5], s37 = x[3] + x[7];
  float t = (x[1] + x[7]) - (x[3] + x[5]);
  float e = s04 + s26, o = s15 + s37;
  F[0] = e + o;
  F[1] = d04 + R2C * t;
  F[2] = s04 - s26;
  F[3] = d04 - R2C * t;
  F[4] = e - o;
}

// Fused input transforms. blocks [0,8192): A ; [8192,8448): X ; [8448,8704): W.
__global__ __launch_bounds__(256) void k_pre(const float* __restrict__ X,
                                             const float* __restrict__ A,
                                             const float* __restrict__ W,
                                             bf16_t* __restrict__ Xft,
                                             bf16_t* __restrict__ Af,
                                             bf16_t* __restrict__ Wft) {
  __shared__ bf16_t tx[40][256];  // X transpose staging: [j*8+h][m]
  int b = blockIdx.x;
  if (b < 8192) {
    // Af[j][n][m] swizzled; two consecutive m per thread (coalesced r/w)
    size_t t = (size_t)b * 256 + threadIdx.x;
    size_t idx = t * 2;  // n*2048 + m
    int n = (int)(idx >> 11), m = (int)(idx & 2047);
    const float4* p = (const float4*)(A + idx * 8);
    float4 q0 = p[0], q1 = p[1], q2 = p[2], q3 = p[3];
    float x0[8] = {q0.x, q0.y, q0.z, q0.w, q1.x, q1.y, q1.z, q1.w};
    float x1[8] = {q2.x, q2.y, q2.z, q2.w, q3.x, q3.y, q3.z, q3.w};
    float F0[5], F1[5];
    fwd5(x0, F0);
    fwd5(x1, F1);
    size_t pos = swz(n, m, 2048);
#pragma unroll
    for (int j = 0; j < 5; j++) {
      bf16x2 v = {(bf16_t)F0[j], (bf16_t)F1[j]};
      *(bf16x2*)(Af + (size_t)j * 4194304 + pos) = v;
    }
  } else if (b < 8448) {
    // Xft[j][h][m]: tile 256 m x 8 h. Coalesced reads -> LDS -> full 16B
    // swizzled chunk writes (no partial-line scatter).
    int bx = b - 8192;
    int m0 = (bx & 7) * 256, h0 = (bx >> 3) * 8;
    int t = threadIdx.x;
    const float4* p = (const float4*)(X + (((size_t)(m0 + t) * 256) + h0) * 8);
#pragma unroll
    for (int h = 0; h < 8; h++) {
      float4 a = p[2 * h], bb = p[2 * h + 1];
      float x[8] = {a.x, a.y, a.z, a.w, bb.x, bb.y, bb.z, bb.w};
      float F[5];
      fwd5(x, F);
#pragma unroll
      for (int j = 0; j < 5; j++) tx[j * 8 + h][t] = (bf16_t)F[j];
    }
    __syncthreads();
#pragma unroll
    for (int it = 0; it < 5; it++) {
      int slot = it * 256 + t;
      int row = slot >> 5, ch = slot & 31;
      int j = row >> 3, hl = row & 7;
      int h = h0 + hl;
      size_t gpos = (size_t)j * 524288 + (size_t)h * 2048 + m0 +
                    ((ch & ~7) << 3) + (((ch & 7) ^ (h & 7)) << 3);
      *(uint4*)(Xft + gpos) = *(const uint4*)(&tx[row][ch * 8]);
    }
  } else {
    // Wft[j][h][h'] = s_j * sum_k W[h'][h][k] c_jk, swizzled (tiny)
    int h = b - 8448;
    int hp = threadIdx.x;
    const float4* p = (const float4*)(W + ((size_t)hp * 256 + h) * 8);
    float4 a = p[0], bb = p[1];
    float x[8] = {a.x, a.y, a.z, a.w, bb.x, bb.y, bb.z, bb.w};
    float F[5];
    fwd5(x, F);
    const float sc[5] = {0.125f, 0.25f, 0.25f, 0.25f, 0.125f};
    size_t pos = swz(h, hp, 256);
#pragma unroll
    for (int j = 0; j < 5; j++)
      Wft[(size_t)j * 65536 + pos] = (bf16_t)(F[j] * sc[j]);
  }
}

// Batched bf16 GEMM, 128x128 tile, BK=64, 4 waves (64x64 each), 16x16x32 MFMA.
// Swizzled operands; global_load_lds width-16 staging, double-buffered LDS with
// raw s_barrier + manual vmcnt(8) so prefetch stays in flight across barriers.
template <typename OutT, bool SWZ_OUT>
__global__ __launch_bounds__(256) void gemm_lds(const bf16_t* __restrict__ A,
                                                const bf16_t* __restrict__ B,
                                                OutT* __restrict__ C, int K,
                                                size_t ap, size_t bp, size_t cp) {
  __shared__ bf16_t sm[4 * 8192];  // [A0|A1|B0|B1], 64KB
  const int j = blockIdx.z;
  const bf16_t* Aj = A + (size_t)j * ap;
  const bf16_t* Bj = B + (size_t)j * bp;
  OutT* Cj = C + (size_t)j * cp;
  const int n0 = blockIdx.x * 128, h0 = blockIdx.y * 128;
  const int tid = threadIdx.x;
  const int wv = tid >> 6, ln = tid & 63;
  const int quad = ln >> 4, l16 = ln & 15;
  const int wn = (wv & 1) * 64, wh = (wv >> 1) * 64;

  const bf16_t* ga[4];
  const bf16_t* gb[4];
  int lo[4];  // element offset inside one 8192-elem buffer (wave-uniform)
#pragma unroll
  for (int s = 0; s < 4; s++) {
    int slot = s * 256 + tid;
    int row = slot >> 3, c16 = slot & 7;
    ga[s] = Aj + (size_t)(n0 + row) * K + c16 * 8;
    gb[s] = Bj + (size_t)(h0 + row) * K + c16 * 8;
    lo[s] = (s * 256 + wv * 64) * 8;
  }

  // prologue: tile 0 -> buffer 0
#pragma unroll
  for (int s = 0; s < 4; s++) {
    async_cp16(ga[s], sm + lo[s]);
    async_cp16(gb[s], sm + 16384 + lo[s]);
  }

  f32x4 acc[4][4] = {};
  for (int kk = 0; kk < K; kk += 64) {
    int p = (kk >> 6) & 1;
    if (kk + 64 < K) {
#pragma unroll
      for (int s = 0; s < 4; s++) {
        async_cp16(ga[s] + kk + 64, sm + (p ^ 1) * 8192 + lo[s]);
        async_cp16(gb[s] + kk + 64, sm + 16384 + (p ^ 1) * 8192 + lo[s]);
      }
      __builtin_amdgcn_s_waitcnt(0xF78);  // vmcnt(8): tile kk landed
    } else {
      __builtin_amdgcn_s_waitcnt(0xF70);  // vmcnt(0): last tile landed
    }
    __builtin_amdgcn_s_barrier();
    const bf16_t* Asp = sm + p * 8192;
    const bf16_t* Bsp = sm + 16384 + p * 8192;
#pragma unroll
    for (int kh = 0; kh < 2; kh++) {
      bf16x8 af[4], bfr[4];
      int c16 = kh * 4 + quad;
#pragma unroll
      for (int i = 0; i < 4; i++) {
        int ra = wn + i * 16 + l16;
        int rb = wh + i * 16 + l16;
        af[i] = *(const bf16x8*)(Asp + ra * 64 + ((c16 ^ (ra & 7)) << 3));
        bfr[i] = *(const bf16x8*)(Bsp + rb * 64 + ((c16 ^ (rb & 7)) << 3));
      }
#pragma unroll
      for (int i = 0; i < 4; i++)
#pragma unroll
        for (int t = 0; t < 4; t++)
          acc[i][t] = __builtin_amdgcn_mfma_f32_16x16x32_bf16(af[i], bfr[t],
                                                              acc[i][t], 0, 0, 0);
    }
    __builtin_amdgcn_s_barrier();  // protect buffer p^1 before next-iter DMA
  }
  // C/D layout: col = lane&15, row = quad*4 + reg
#pragma unroll
  for (int i = 0; i < 4; i++) {
#pragma unroll
    for (int t = 0; t < 4; t++) {
      int hc = h0 + wh + t * 16 + l16;
#pragma unroll
      for (int rg = 0; rg < 4; rg++) {
        int nr = n0 + wn + i * 16 + quad * 4 + rg;
        size_t off = SWZ_OUT ? swz(nr, hc, 256) : (size_t)nr * 256 + hc;
        Cj[off] = (OutT)acc[i][t][rg];
      }
    }
  }
}

// out[n][h][k] = sum_j c_jk * C2_j[n][h]  (ifft scales folded into Wft)
__global__ __launch_bounds__(256) void k_combine(const float* __restrict__ C2,
                                                 float* __restrict__ out) {
  size_t idx = (size_t)blockIdx.x * 256 + threadIdx.x;
  float c0 = C2[idx];
  float c1 = C2[524288 + idx];
  float c2 = C2[2 * 524288 + idx];
  float c3 = C2[3 * 524288 + idx];
  float c4 = C2[4 * 524288 + idx];
  float o0 = c0 + c1 + c2 + c3 + c4;
  float o4 = c0 - c1 + c2 - c3 + c4;
  float o2 = c0 - c2 + c4;
  float rt = R2C * (c1 - c3);
  float o1 = c0 + rt - c4;
  float o3 = c0 - rt - c4;
  float4* op = (float4*)(out + idx * 8);
  op[0] = make_float4(o0, o1, o2, o3);
  op[1] = make_float4(o4, o3, o2, o1);
}

extern "C" void kernel_launch(void* const* d_in, const int* in_sizes, int n_in,
                              void* d_out, int out_size, void* d_ws, size_t ws_size,
                              hipStream_t stream) {
  const float* X = (const float*)d_in[0];   // (2048,256,8)
  const float* A = (const float*)d_in[1];   // (2048,2048,8)
  const float* W = (const float*)d_in[2];   // (256,256,8)
  float* out = (float*)d_out;               // (2048,256,8)
  char* ws = (char*)d_ws;

  bf16_t* Af  = (bf16_t*)(ws);              // 5*2048*2048*2 = 41943040
  bf16_t* Xft = (bf16_t*)(ws + 41943040);   // 5*256*2048*2  =  5242880
  bf16_t* Wft = (bf16_t*)(ws + 47185920);   // 5*256*256*2   =   655360
  bf16_t* C1  = (bf16_t*)(ws + 47841280);   // 5*2048*256*2  =  5242880
  float*  C2  = (float*) (ws + 53084160);   // 5*2048*256*4  = 10485760
                                            // total 63569920 B

  k_pre<<<dim3(8704), 256, 0, stream>>>(X, A, W, Xft, Af, Wft);
  gemm_lds<bf16_t, true><<<dim3(16, 2, 5), 256, 0, stream>>>(
      Af, Xft, C1, 2048, (size_t)4194304, (size_t)524288, (size_t)524288);
  gemm_lds<float, false><<<dim3(16, 2, 5), 256, 0, stream>>>(
      C1, Wft, C2, 256, (size_t)524288, (size_t)65536, (size_t)524288);
  k_combine<<<dim3(2048), 256, 0, stream>>>(C2, out);
}